// Round 1
// 774.447 us; speedup vs baseline: 1.0299x; 1.0299x over previous
//
#include <hip/hip_runtime.h>

#define H 128
#define NR 6
#define MT 128          // MLP rows per block
#define HS 136          // padded k-stride (shorts) for LDS bf16 tiles

typedef __attribute__((ext_vector_type(8))) short short8_t;
typedef __attribute__((ext_vector_type(4))) float f32x4;

__device__ __forceinline__ float silu_f(float v) {
    return v / (1.0f + __expf(-v));
}

// ----- bf16 split helpers (RNE, finite inputs only) -----
__device__ __forceinline__ unsigned short bf16_rne(float f) {
    unsigned u = __float_as_uint(f);
    u += 0x7FFF + ((u >> 16) & 1);
    return (unsigned short)(u >> 16);
}
__device__ __forceinline__ float bf16_to_f(unsigned short s) {
    return __uint_as_float(((unsigned)s) << 16);
}

// ------------------------------------------------------------ histogram
__global__ __launch_bounds__(256) void hist_k(const int* __restrict__ idx,
                                              int* __restrict__ counts, int E) {
    int i = blockIdx.x * 256 + threadIdx.x;
    if (i < E) atomicAdd(&counts[idx[i]], 1);
}

// ---------------------------------------- coalesced single-block scan
__global__ __launch_bounds__(1024) void scan_k(const int* __restrict__ counts,
                                               int* __restrict__ offsets, int N) {
    __shared__ int wsum[16];
    __shared__ int runv;
    const int tid = threadIdx.x, lane = tid & 63, wv = tid >> 6;
    if (tid == 0) runv = 0;
    __syncthreads();
    for (int base = 0; base < N; base += 1024) {
        const int j = base + tid;
        const int v_in = (j < N) ? counts[j] : 0;
        int v = v_in;
        #pragma unroll
        for (int d = 1; d < 64; d <<= 1) {
            int u = __shfl_up(v, d);
            if (lane >= d) v += u;
        }
        if (lane == 63) wsum[wv] = v;
        __syncthreads();
        if (tid < 16) {
            int s = wsum[tid];
            #pragma unroll
            for (int d = 1; d < 16; d <<= 1) {
                int u = __shfl_up(s, d);
                if (tid >= d) s += u;
            }
            wsum[tid] = s;
        }
        __syncthreads();
        const int wexcl = (wv == 0) ? 0 : wsum[wv - 1];
        const int r0 = runv;
        if (j < N) offsets[j] = r0 + wexcl + (v - v_in);
        const int tot = wsum[15];
        __syncthreads();               // all reads of runv/wsum done
        if (tid == 0) runv = r0 + tot;
        __syncthreads();               // update visible before next tile
    }
    if (tid == 0) offsets[N] = runv;
}

// ------------------------------------------------------------ CSR fill
__global__ __launch_bounds__(256) void fill_k(const int* __restrict__ idx,
                                              const int* __restrict__ offsets,
                                              int* __restrict__ cursor,
                                              int* __restrict__ elist, int E) {
    int i = blockIdx.x * 256 + threadIdx.x;
    if (i < E) {
        int node = idx[i];
        int pos = atomicAdd(&cursor[node], 1);
        elist[offsets[node] + pos] = i;
    }
}

// -------------------------------------------- weight pre-split (once)
// dst layout: [layer][hi: H*H shorts][lo: H*H shorts]
__global__ __launch_bounds__(256) void wsplit_k(
    const float* __restrict__ W1, const float* __restrict__ W2,
    const float* __restrict__ W3, const float* __restrict__ Wo,
    unsigned short* __restrict__ dst)
{
    const float* W = (blockIdx.y == 0) ? W1 : (blockIdx.y == 1) ? W2
                   : (blockIdx.y == 2) ? W3 : Wo;
    unsigned short* hi = dst + (size_t)blockIdx.y * 2 * H * H;
    unsigned short* lo = hi + H * H;
    const int i = (blockIdx.x * 256 + threadIdx.x) * 4;
    if (i < H * H) {
        const float4 v = *(const float4*)(W + i);
        ushort4 h4, l4;
        h4.x = bf16_rne(v.x); l4.x = bf16_rne(v.x - bf16_to_f(h4.x));
        h4.y = bf16_rne(v.y); l4.y = bf16_rne(v.y - bf16_to_f(h4.y));
        h4.z = bf16_rne(v.z); l4.z = bf16_rne(v.z - bf16_to_f(h4.z));
        h4.w = bf16_rne(v.w); l4.w = bf16_rne(v.w - bf16_to_f(h4.w));
        *(ushort4*)&hi[i] = h4;
        *(ushort4*)&lo[i] = l4;
    }
}

// =================================================================== MLP
// Split-bf16 MFMA (hi*Whi + hi*Wlo + lo*Whi), 16x16x32 bf16.
// 512 threads = 8 waves; wave wv owns 16-row block wv. 1 block/CU (LDS).
// A-frag: A[m=lane&15][k=quad*8+j]; B-frag: W[c=lane&15][k=quad*8+j];
// D: col=lane&15, row=quad*4+reg  [m89/m91-verified].

__device__ __forceinline__ void stage_w_pre(const unsigned short* __restrict__ g,
        unsigned short* w_hi, unsigned short* w_lo, int t)
{
    const unsigned short* hi_g = g;
    const unsigned short* lo_g = g + H * H;
    for (int i = t * 8; i < H * H; i += 4096) {
        const int c = i >> 7, k = i & 127;
        *(short8_t*)&w_hi[c * HS + k] = *(const short8_t*)&hi_g[i];
        *(short8_t*)&w_lo[c * HS + k] = *(const short8_t*)&lo_g[i];
    }
}

__device__ __forceinline__ void compute_gemm(
    const unsigned short* h_hi, const unsigned short* h_lo,
    const unsigned short* w_hi, const unsigned short* w_lo,
    const float* bl, int wv, int lr, int quad, f32x4 (&acc)[8])
{
    short8_t a_hi[4], a_lo[4];
    const int row = wv * 16 + lr;
    #pragma unroll
    for (int kb = 0; kb < 4; ++kb) {
        const int off = row * HS + kb * 32 + quad * 8;
        a_hi[kb] = *(const short8_t*)&h_hi[off];
        a_lo[kb] = *(const short8_t*)&h_lo[off];
    }
    #pragma unroll
    for (int ct = 0; ct < 8; ct += 2) {
        const int c0 = ct * 16 + lr, c1 = (ct + 1) * 16 + lr;
        const float bb0 = bl[c0], bb1 = bl[c1];
        f32x4 A0 = {bb0, bb0, bb0, bb0}, A1 = {bb1, bb1, bb1, bb1};
        short8_t b0h[4], b0l[4], b1h[4], b1l[4];
        #pragma unroll
        for (int kb = 0; kb < 4; ++kb) {
            const int o0 = c0 * HS + kb * 32 + quad * 8;
            const int o1 = c1 * HS + kb * 32 + quad * 8;
            b0h[kb] = *(const short8_t*)&w_hi[o0];
            b0l[kb] = *(const short8_t*)&w_lo[o0];
            b1h[kb] = *(const short8_t*)&w_hi[o1];
            b1l[kb] = *(const short8_t*)&w_lo[o1];
        }
        #pragma unroll
        for (int kb = 0; kb < 4; ++kb) {
            A0 = __builtin_amdgcn_mfma_f32_16x16x32_bf16(a_hi[kb], b0h[kb], A0, 0, 0, 0);
            A1 = __builtin_amdgcn_mfma_f32_16x16x32_bf16(a_hi[kb], b1h[kb], A1, 0, 0, 0);
            A0 = __builtin_amdgcn_mfma_f32_16x16x32_bf16(a_hi[kb], b0l[kb], A0, 0, 0, 0);
            A1 = __builtin_amdgcn_mfma_f32_16x16x32_bf16(a_hi[kb], b1l[kb], A1, 0, 0, 0);
            A0 = __builtin_amdgcn_mfma_f32_16x16x32_bf16(a_lo[kb], b0h[kb], A0, 0, 0, 0);
            A1 = __builtin_amdgcn_mfma_f32_16x16x32_bf16(a_lo[kb], b1h[kb], A1, 0, 0, 0);
        }
        acc[ct] = A0;
        acc[ct + 1] = A1;
    }
}

__device__ __forceinline__ void epilogue_silu(
    unsigned short* h_hi, unsigned short* h_lo,
    f32x4 (&acc)[8], int wv, int lr, int quad)
{
    #pragma unroll
    for (int ct = 0; ct < 8; ++ct)
        #pragma unroll
        for (int r = 0; r < 4; ++r) {
            const int row = wv * 16 + quad * 4 + r;
            const int col = ct * 16 + lr;
            const float v = silu_f(acc[ct][r]);
            const unsigned short hi = bf16_rne(v);
            h_hi[row * HS + col] = hi;
            h_lo[row * HS + col] = bf16_rne(v - bf16_to_f(hi));
        }
}

// Fused: gather (CSR edge reduce, half-wave float4) -> 4-layer MFMA MLP.
// Each wave gathers its own 16 rows directly into the LDS h tiles.
__global__ __launch_bounds__(512, 2) void fused_mlp(
    const float* __restrict__ x, const float* __restrict__ rbf,
    const float* __restrict__ W_rbf,
    const int* __restrict__ offsets, const int* __restrict__ elist,
    const unsigned short* __restrict__ wsp,
    const float* __restrict__ b1, const float* __restrict__ b2,
    const float* __restrict__ b3,
    float* __restrict__ out, int N)
{
    __shared__ unsigned short h_hi[H * HS], h_lo[H * HS];   // 34 KB each
    __shared__ unsigned short w_hi[H * HS], w_lo[H * HS];   // 34 KB each
    __shared__ float bl[H];

    const int t = threadIdx.x;
    const int lane = t & 63;
    const int wv = t >> 6;          // 0..7: 16-row block
    const int lr = lane & 15;
    const int quad = lane >> 4;
    const int sub = lane >> 5;      // half-wave id (edge parity)
    const int l32 = lane & 31;      // 4 columns l32*4 .. +3
    const int row0 = blockIdx.x * MT;

    // ---------------- per-lane W_rbf block: rows (=output cols) l32*4..+3
    const float4* wp = (const float4*)(W_rbf + l32 * 24);
    const float4 w0 = wp[0], w1 = wp[1], w2 = wp[2], w3 = wp[3],
                 w4 = wp[4], w5 = wp[5];
    const float wr[4][NR] = {
        {w0.x, w0.y, w0.z, w0.w, w1.x, w1.y},
        {w1.z, w1.w, w2.x, w2.y, w2.z, w2.w},
        {w3.x, w3.y, w3.z, w3.w, w4.x, w4.y},
        {w4.z, w4.w, w5.x, w5.y, w5.z, w5.w}};

    // ---------------- gather phase: wave wv fills LDS rows wv*16 .. +15
    for (int i = 0; i < 16; ++i) {
        const int node = row0 + wv * 16 + i;
        float4 ga = make_float4(0.f, 0.f, 0.f, 0.f);
        if (node < N) {
            const int beg = offsets[node], end = offsets[node + 1];
            for (int base = beg; base < end; base += 64) {
                const int cnt = min(64, end - base);
                const int e_lane = (lane < cnt) ? elist[base + lane] : 0;
                for (int p = 0; p < cnt; p += 8) {
                    int ev[4];
                    bool val[4];
                    float4 xv[4];
                    float2 rv[4][3];
                    #pragma unroll
                    for (int q = 0; q < 4; ++q) {
                        const int slot = p + 2 * q + sub;
                        val[q] = slot < cnt;
                        ev[q] = __shfl(e_lane, val[q] ? slot : cnt - 1);
                    }
                    #pragma unroll
                    for (int q = 0; q < 4; ++q) {
                        const size_t e = (size_t)ev[q];
                        xv[q] = *(const float4*)(x + e * H + l32 * 4);
                        const float2* rp = (const float2*)(rbf + e * NR);
                        rv[q][0] = rp[0]; rv[q][1] = rp[1]; rv[q][2] = rp[2];
                    }
                    #pragma unroll
                    for (int q = 0; q < 4; ++q) {
                        if (!val[q]) continue;
                        const float rr[NR] = {rv[q][0].x, rv[q][0].y, rv[q][1].x,
                                              rv[q][1].y, rv[q][2].x, rv[q][2].y};
                        float s0 = 0.f, s1 = 0.f, s2 = 0.f, s3 = 0.f;
                        #pragma unroll
                        for (int j = 0; j < NR; ++j) {
                            s0 += rr[j] * wr[0][j];
                            s1 += rr[j] * wr[1][j];
                            s2 += rr[j] * wr[2][j];
                            s3 += rr[j] * wr[3][j];
                        }
                        ga.x += s0 * xv[q].x;
                        ga.y += s1 * xv[q].y;
                        ga.z += s2 * xv[q].z;
                        ga.w += s3 * xv[q].w;
                    }
                }
            }
            // combine the two half-wave partial sums
            ga.x += __shfl_xor(ga.x, 32);
            ga.y += __shfl_xor(ga.y, 32);
            ga.z += __shfl_xor(ga.z, 32);
            ga.w += __shfl_xor(ga.w, 32);
        }
        if (sub == 0) {
            ushort4 h4, l4;
            h4.x = bf16_rne(ga.x); l4.x = bf16_rne(ga.x - bf16_to_f(h4.x));
            h4.y = bf16_rne(ga.y); l4.y = bf16_rne(ga.y - bf16_to_f(h4.y));
            h4.z = bf16_rne(ga.z); l4.z = bf16_rne(ga.z - bf16_to_f(h4.z));
            h4.w = bf16_rne(ga.w); l4.w = bf16_rne(ga.w - bf16_to_f(h4.w));
            const int off = (wv * 16 + i) * HS + l32 * 4;
            *(ushort4*)&h_hi[off] = h4;
            *(ushort4*)&h_lo[off] = l4;
        }
    }

    // ---------------- MLP phases (pre-split weights: pure LDS copy)
    stage_w_pre(wsp, w_hi, w_lo, t);
    if (t < H) bl[t] = b1[t];
    __syncthreads();

    f32x4 acc[8];

    compute_gemm(h_hi, h_lo, w_hi, w_lo, bl, wv, lr, quad, acc);
    __syncthreads();
    epilogue_silu(h_hi, h_lo, acc, wv, lr, quad);
    stage_w_pre(wsp + 32768, w_hi, w_lo, t);
    if (t < H) bl[t] = b2[t];
    __syncthreads();

    compute_gemm(h_hi, h_lo, w_hi, w_lo, bl, wv, lr, quad, acc);
    __syncthreads();
    epilogue_silu(h_hi, h_lo, acc, wv, lr, quad);
    stage_w_pre(wsp + 65536, w_hi, w_lo, t);
    if (t < H) bl[t] = b3[t];
    __syncthreads();

    compute_gemm(h_hi, h_lo, w_hi, w_lo, bl, wv, lr, quad, acc);
    __syncthreads();
    epilogue_silu(h_hi, h_lo, acc, wv, lr, quad);
    stage_w_pre(wsp + 98304, w_hi, w_lo, t);
    if (t < H) bl[t] = 0.f;
    __syncthreads();

    compute_gemm(h_hi, h_lo, w_hi, w_lo, bl, wv, lr, quad, acc);

    #pragma unroll
    for (int ct = 0; ct < 8; ++ct)
        #pragma unroll
        for (int r = 0; r < 4; ++r) {
            const int row = row0 + wv * 16 + quad * 4 + r;
            if (row < N) out[(size_t)row * H + ct * 16 + lr] = acc[ct][r];
        }
}

// ---------------------------------------------------------------- launch
static inline size_t align256(size_t v) { return (v + 255) & ~(size_t)255; }

extern "C" void kernel_launch(void* const* d_in, const int* in_sizes, int n_in,
                              void* d_out, int out_size, void* d_ws, size_t ws_size,
                              hipStream_t stream) {
    const float* x     = (const float*)d_in[0];
    const float* rbf   = (const float*)d_in[1];
    const int*   idx   = (const int*)d_in[2];
    const float* W_rbf = (const float*)d_in[4];
    const float* W1    = (const float*)d_in[5];
    const float* b1    = (const float*)d_in[6];
    const float* W2    = (const float*)d_in[7];
    const float* b2    = (const float*)d_in[8];
    const float* W3    = (const float*)d_in[9];
    const float* b3    = (const float*)d_in[10];
    const float* Wo    = (const float*)d_in[11];
    float* out = (float*)d_out;

    const int E = in_sizes[0] / H;
    const int N = out_size / H;

    char* ws = (char*)d_ws;
    size_t off = 0;
    unsigned short* wsp = (unsigned short*)(ws + off);
    off = align256(off + (size_t)4 * 2 * H * H * sizeof(unsigned short));
    int* counts  = (int*)(ws + off);   off = align256(off + (size_t)N * 4);
    int* cursor  = (int*)(ws + off);   off = align256(off + (size_t)N * 4);
    int* offsets = (int*)(ws + off);   off = align256(off + (size_t)(N + 1) * 4);
    int* elist   = (int*)(ws + off);   off = align256(off + (size_t)E * 4);

    hipMemsetAsync(counts, 0, (char*)offsets - (char*)counts, stream);

    wsplit_k<<<dim3(16, 4), 256, 0, stream>>>(W1, W2, W3, Wo, wsp);
    hist_k<<<(E + 255) / 256, 256, 0, stream>>>(idx, counts, E);
    scan_k<<<1, 1024, 0, stream>>>(counts, offsets, N);
    fill_k<<<(E + 255) / 256, 256, 0, stream>>>(idx, offsets, cursor, elist, E);
    fused_mlp<<<(N + MT - 1) / MT, 512, 0, stream>>>(
        x, rbf, W_rbf, offsets, elist, wsp, b1, b2, b3, out, N);
}

// Round 2
// 751.265 us; speedup vs baseline: 1.0617x; 1.0309x over previous
//
#include <hip/hip_runtime.h>

#define H 128
#define NR 6
#define MT 128          // MLP rows per block
#define HS 136          // padded k-stride (shorts) for LDS bf16 tiles

typedef __attribute__((ext_vector_type(8))) short short8_t;
typedef __attribute__((ext_vector_type(4))) float f32x4;

__device__ __forceinline__ float silu_f(float v) {
    return v / (1.0f + __expf(-v));
}

// ----- bf16 split helpers (RNE, finite inputs only) -----
__device__ __forceinline__ unsigned short bf16_rne(float f) {
    unsigned u = __float_as_uint(f);
    u += 0x7FFF + ((u >> 16) & 1);
    return (unsigned short)(u >> 16);
}
__device__ __forceinline__ float bf16_to_f(unsigned short s) {
    return __uint_as_float(((unsigned)s) << 16);
}

// ------------------------------------------------------------ histogram
__global__ __launch_bounds__(256) void hist_k(const int* __restrict__ idx,
                                              int* __restrict__ counts, int E) {
    const int i0 = (blockIdx.x * 256 + threadIdx.x) * 4;
    if (i0 + 3 < E) {
        const int4 v = *(const int4*)(idx + i0);
        atomicAdd(&counts[v.x], 1);
        atomicAdd(&counts[v.y], 1);
        atomicAdd(&counts[v.z], 1);
        atomicAdd(&counts[v.w], 1);
    } else {
        for (int i = i0; i < E; ++i) atomicAdd(&counts[idx[i]], 1);
    }
}

// ------------------------- coalesced single-block scan, int4 per thread
__global__ __launch_bounds__(1024) void scan_k(const int* __restrict__ counts,
                                               int* __restrict__ offsets, int N) {
    __shared__ int wsum[16];
    __shared__ int runv;
    const int tid = threadIdx.x, lane = tid & 63, wv = tid >> 6;
    if (tid == 0) runv = 0;
    __syncthreads();
    for (int base = 0; base < N; base += 4096) {
        const int j0 = base + tid * 4;
        int4 v = make_int4(0, 0, 0, 0);
        if (j0 + 3 < N) v = *(const int4*)(counts + j0);
        else {
            if (j0     < N) v.x = counts[j0];
            if (j0 + 1 < N) v.y = counts[j0 + 1];
            if (j0 + 2 < N) v.z = counts[j0 + 2];
        }
        const int e1 = v.x, e2 = e1 + v.y, e3 = e2 + v.z, tot = e3 + v.w;
        int vincl = tot;
        #pragma unroll
        for (int d = 1; d < 64; d <<= 1) {
            int u = __shfl_up(vincl, d);
            if (lane >= d) vincl += u;
        }
        if (lane == 63) wsum[wv] = vincl;
        __syncthreads();
        if (tid < 16) {
            int s = wsum[tid];
            #pragma unroll
            for (int d = 1; d < 16; d <<= 1) {
                int u = __shfl_up(s, d);
                if (tid >= d) s += u;
            }
            wsum[tid] = s;
        }
        __syncthreads();
        const int wexcl = (wv == 0) ? 0 : wsum[wv - 1];
        const int r0 = runv;
        const int be = r0 + wexcl + (vincl - tot);
        if (j0 + 3 < N) {
            *(int4*)(offsets + j0) = make_int4(be, be + e1, be + e2, be + e3);
        } else {
            if (j0     < N) offsets[j0]     = be;
            if (j0 + 1 < N) offsets[j0 + 1] = be + e1;
            if (j0 + 2 < N) offsets[j0 + 2] = be + e2;
        }
        const int tottile = wsum[15];
        __syncthreads();               // all reads of runv/wsum done
        if (tid == 0) runv = r0 + tottile;
        __syncthreads();               // update visible before next tile
    }
    if (tid == 0) offsets[N] = runv;
}

// ------------------------------------------------------------ CSR fill
__global__ __launch_bounds__(256) void fill_k(const int* __restrict__ idx,
                                              const int* __restrict__ offsets,
                                              int* __restrict__ cursor,
                                              int* __restrict__ elist, int E) {
    const int i0 = (blockIdx.x * 256 + threadIdx.x) * 4;
    if (i0 + 3 < E) {
        const int4 v = *(const int4*)(idx + i0);
        const int nd[4] = {v.x, v.y, v.z, v.w};
        #pragma unroll
        for (int q = 0; q < 4; ++q) {
            const int pos = atomicAdd(&cursor[nd[q]], 1);
            elist[offsets[nd[q]] + pos] = i0 + q;
        }
    } else {
        for (int i = i0; i < E; ++i) {
            const int node = idx[i];
            const int pos = atomicAdd(&cursor[node], 1);
            elist[offsets[node] + pos] = i;
        }
    }
}

// -------------------------------------------- weight pre-split (once)
// dst layout: [layer][hi: H*H shorts][lo: H*H shorts]
__global__ __launch_bounds__(256) void wsplit_k(
    const float* __restrict__ W1, const float* __restrict__ W2,
    const float* __restrict__ W3, const float* __restrict__ Wo,
    unsigned short* __restrict__ dst)
{
    const float* W = (blockIdx.y == 0) ? W1 : (blockIdx.y == 1) ? W2
                   : (blockIdx.y == 2) ? W3 : Wo;
    unsigned short* hi = dst + (size_t)blockIdx.y * 2 * H * H;
    unsigned short* lo = hi + H * H;
    const int i = (blockIdx.x * 256 + threadIdx.x) * 4;
    if (i < H * H) {
        const float4 v = *(const float4*)(W + i);
        ushort4 h4, l4;
        h4.x = bf16_rne(v.x); l4.x = bf16_rne(v.x - bf16_to_f(h4.x));
        h4.y = bf16_rne(v.y); l4.y = bf16_rne(v.y - bf16_to_f(h4.y));
        h4.z = bf16_rne(v.z); l4.z = bf16_rne(v.z - bf16_to_f(h4.z));
        h4.w = bf16_rne(v.w); l4.w = bf16_rne(v.w - bf16_to_f(h4.w));
        *(ushort4*)&hi[i] = h4;
        *(ushort4*)&lo[i] = l4;
    }
}

// =================================================================== MLP
// Split-bf16 MFMA (hi*Whi + hi*Wlo + lo*Whi), 16x16x32 bf16.
// 512 threads = 8 waves; wave wv owns 16-row block wv. 1 block/CU (LDS).
// A-frag: A[m=lane&15][k=quad*8+j]; B-frag: W[c=lane&15][k=quad*8+j];
// D: col=lane&15, row=quad*4+reg  [m89/m91-verified].

__device__ __forceinline__ void stage_w_pre(const unsigned short* __restrict__ g,
        unsigned short* w_hi, unsigned short* w_lo, int t)
{
    const unsigned short* hi_g = g;
    const unsigned short* lo_g = g + H * H;
    for (int i = t * 8; i < H * H; i += 4096) {
        const int c = i >> 7, k = i & 127;
        *(short8_t*)&w_hi[c * HS + k] = *(const short8_t*)&hi_g[i];
        *(short8_t*)&w_lo[c * HS + k] = *(const short8_t*)&lo_g[i];
    }
}

__device__ __forceinline__ void compute_gemm(
    const unsigned short* h_hi, const unsigned short* h_lo,
    const unsigned short* w_hi, const unsigned short* w_lo,
    const float* bl, int wv, int lr, int quad, f32x4 (&acc)[8])
{
    short8_t a_hi[4], a_lo[4];
    const int row = wv * 16 + lr;
    #pragma unroll
    for (int kb = 0; kb < 4; ++kb) {
        const int off = row * HS + kb * 32 + quad * 8;
        a_hi[kb] = *(const short8_t*)&h_hi[off];
        a_lo[kb] = *(const short8_t*)&h_lo[off];
    }
    #pragma unroll
    for (int ct = 0; ct < 8; ct += 2) {
        const int c0 = ct * 16 + lr, c1 = (ct + 1) * 16 + lr;
        const float bb0 = bl[c0], bb1 = bl[c1];
        f32x4 A0 = {bb0, bb0, bb0, bb0}, A1 = {bb1, bb1, bb1, bb1};
        short8_t b0h[4], b0l[4], b1h[4], b1l[4];
        #pragma unroll
        for (int kb = 0; kb < 4; ++kb) {
            const int o0 = c0 * HS + kb * 32 + quad * 8;
            const int o1 = c1 * HS + kb * 32 + quad * 8;
            b0h[kb] = *(const short8_t*)&w_hi[o0];
            b0l[kb] = *(const short8_t*)&w_lo[o0];
            b1h[kb] = *(const short8_t*)&w_hi[o1];
            b1l[kb] = *(const short8_t*)&w_lo[o1];
        }
        #pragma unroll
        for (int kb = 0; kb < 4; ++kb) {
            A0 = __builtin_amdgcn_mfma_f32_16x16x32_bf16(a_hi[kb], b0h[kb], A0, 0, 0, 0);
            A1 = __builtin_amdgcn_mfma_f32_16x16x32_bf16(a_hi[kb], b1h[kb], A1, 0, 0, 0);
            A0 = __builtin_amdgcn_mfma_f32_16x16x32_bf16(a_hi[kb], b0l[kb], A0, 0, 0, 0);
            A1 = __builtin_amdgcn_mfma_f32_16x16x32_bf16(a_hi[kb], b1l[kb], A1, 0, 0, 0);
            A0 = __builtin_amdgcn_mfma_f32_16x16x32_bf16(a_lo[kb], b0h[kb], A0, 0, 0, 0);
            A1 = __builtin_amdgcn_mfma_f32_16x16x32_bf16(a_lo[kb], b1h[kb], A1, 0, 0, 0);
        }
        acc[ct] = A0;
        acc[ct + 1] = A1;
    }
}

__device__ __forceinline__ void epilogue_silu(
    unsigned short* h_hi, unsigned short* h_lo,
    f32x4 (&acc)[8], int wv, int lr, int quad)
{
    #pragma unroll
    for (int ct = 0; ct < 8; ++ct)
        #pragma unroll
        for (int r = 0; r < 4; ++r) {
            const int row = wv * 16 + quad * 4 + r;
            const int col = ct * 16 + lr;
            const float v = silu_f(acc[ct][r]);
            const unsigned short hi = bf16_rne(v);
            h_hi[row * HS + col] = hi;
            h_lo[row * HS + col] = bf16_rne(v - bf16_to_f(hi));
        }
}

// Fused: edge-streamed CSR gather -> 4-layer MFMA MLP.
// Block owns 128 node-rows = a CONTIGUOUS elist range. 16 half-waves walk
// contiguous sub-chunks: batch-load 32 edge ids + rbf rows lane-parallel,
// shfl-broadcast, register-accumulate per node-run, LDS-atomic flush at
// node boundaries into fp32 hacc (aliased over the weight LDS region).
__global__ __launch_bounds__(512, 2) void fused_mlp(
    const float* __restrict__ x, const float* __restrict__ rbf,
    const float* __restrict__ W_rbf,
    const int* __restrict__ offsets, const int* __restrict__ elist,
    const unsigned short* __restrict__ wsp,
    const float* __restrict__ b1, const float* __restrict__ b2,
    const float* __restrict__ b3,
    float* __restrict__ out, int N)
{
    __shared__ __align__(16) unsigned short smem[4 * H * HS];  // 136 KB
    unsigned short* h_hi = smem;
    unsigned short* h_lo = smem + H * HS;
    unsigned short* w_hi = smem + 2 * H * HS;
    unsigned short* w_lo = smem + 3 * H * HS;
    float* hacc = (float*)(smem + 2 * H * HS);   // 64 KB alias over w tiles
    __shared__ float bl[H];
    __shared__ int off_s[MT + 1];

    const int t = threadIdx.x;
    const int lane = t & 63;
    const int wv = t >> 6;          // 0..7
    const int lr = lane & 15;
    const int quad = lane >> 4;
    const int sub = lane >> 5;      // half-wave within wave
    const int l32 = lane & 31;      // owns cols l32*4 .. +3
    const int hw = t >> 5;          // 0..15 half-wave id in block
    const int row0 = blockIdx.x * MT;

    // per-lane W_rbf rows (output cols l32*4..+3): 24 consecutive floats
    const float4* wp = (const float4*)(W_rbf + l32 * 24);
    const float4 w0 = wp[0], w1 = wp[1], w2 = wp[2], w3 = wp[3],
                 w4 = wp[4], w5 = wp[5];
    const float wr[4][NR] = {
        {w0.x, w0.y, w0.z, w0.w, w1.x, w1.y},
        {w1.z, w1.w, w2.x, w2.y, w2.z, w2.w},
        {w3.x, w3.y, w3.z, w3.w, w4.x, w4.y},
        {w4.z, w4.w, w5.x, w5.y, w5.z, w5.w}};

    // zero fp32 accum tile + stage this block's offset window
    for (int i = t * 4; i < H * H; i += 2048)
        *(float4*)&hacc[i] = make_float4(0.f, 0.f, 0.f, 0.f);
    for (int k = t; k <= MT; k += 512)
        off_s[k] = offsets[min(row0 + k, N)];
    __syncthreads();

    const int ebeg = off_s[0], eend = off_s[MT];
    const int C = (eend - ebeg + 15) >> 4;        // chunk per half-wave
    const int s0 = ebeg + hw * C;
    const int e_lim = min(s0 + C, eend);

    if (s0 < e_lim) {
        // start node: largest nl with off_s[nl] <= s0 (uniform per half-wave)
        int lo = 0, hi = MT;
        while (hi - lo > 1) {
            const int mid = (lo + hi) >> 1;
            if (off_s[mid] <= s0) lo = mid; else hi = mid;
        }
        int nl = lo;
        int nxt = off_s[nl + 1];
        float4 acc = make_float4(0.f, 0.f, 0.f, 0.f);
        bool dirty = false;

        // batch 0: lane-parallel edge ids + rbf rows
        int eid;
        float2 ra, rb, rc;
        {
            const int p = s0 + l32;
            const int e = (p < e_lim) ? elist[p] : 0;
            eid = e;
            const float2* rp = (const float2*)(rbf + (size_t)e * NR);
            ra = rp[0]; rb = rp[1]; rc = rp[2];
        }

        for (int b = s0; b < e_lim; b += 32) {
            const int m = min(32, e_lim - b);
            // prefetch next batch
            int eidN = 0;
            float2 raN = make_float2(0.f, 0.f), rbN = raN, rcN = raN;
            {
                const int p = b + 32 + l32;
                if (b + 32 < e_lim) {
                    const int e = (p < e_lim) ? elist[p] : 0;
                    eidN = e;
                    const float2* rp = (const float2*)(rbf + (size_t)e * NR);
                    raN = rp[0]; rbN = rp[1]; rcN = rp[2];
                }
            }
            for (int k0 = 0; k0 < m; k0 += 4) {
                int ee[4];
                float rr[4][NR];
                bool va[4];
                #pragma unroll
                for (int q = 0; q < 4; ++q) {
                    const int kq = k0 + q;
                    va[q] = kq < m;
                    const int srcl = sub * 32 + (va[q] ? kq : 0);
                    ee[q] = __shfl(eid, srcl);
                    rr[q][0] = __shfl(ra.x, srcl); rr[q][1] = __shfl(ra.y, srcl);
                    rr[q][2] = __shfl(rb.x, srcl); rr[q][3] = __shfl(rb.y, srcl);
                    rr[q][4] = __shfl(rc.x, srcl); rr[q][5] = __shfl(rc.y, srcl);
                }
                float4 xv[4];
                #pragma unroll
                for (int q = 0; q < 4; ++q)
                    xv[q] = *(const float4*)(x + (size_t)ee[q] * H + l32 * 4);
                #pragma unroll
                for (int q = 0; q < 4; ++q) {
                    if (va[q]) {
                        const int pos = b + k0 + q;
                        while (pos >= nxt) {          // node boundary: flush
                            if (dirty) {
                                float* hp = &hacc[nl * H + l32 * 4];
                                atomicAdd(hp + 0, acc.x);
                                atomicAdd(hp + 1, acc.y);
                                atomicAdd(hp + 2, acc.z);
                                atomicAdd(hp + 3, acc.w);
                                acc = make_float4(0.f, 0.f, 0.f, 0.f);
                                dirty = false;
                            }
                            ++nl;
                            nxt = off_s[nl + 1];
                        }
                        float sA = 0.f, sB = 0.f, sC = 0.f, sD = 0.f;
                        #pragma unroll
                        for (int j = 0; j < NR; ++j) {
                            sA += rr[q][j] * wr[0][j];
                            sB += rr[q][j] * wr[1][j];
                            sC += rr[q][j] * wr[2][j];
                            sD += rr[q][j] * wr[3][j];
                        }
                        acc.x += sA * xv[q].x;
                        acc.y += sB * xv[q].y;
                        acc.z += sC * xv[q].z;
                        acc.w += sD * xv[q].w;
                        dirty = true;
                    }
                }
            }
            eid = eidN; ra = raN; rb = rbN; rc = rcN;
        }
        if (dirty) {
            float* hp = &hacc[nl * H + l32 * 4];
            atomicAdd(hp + 0, acc.x);
            atomicAdd(hp + 1, acc.y);
            atomicAdd(hp + 2, acc.z);
            atomicAdd(hp + 3, acc.w);
        }
    }
    __syncthreads();

    // convert fp32 accum -> split bf16 h tiles (h region is disjoint)
    for (int i = t * 4; i < H * H; i += 2048) {
        const float4 v = *(const float4*)&hacc[i];
        const int r = i >> 7, k = i & 127;
        ushort4 h4, l4;
        h4.x = bf16_rne(v.x); l4.x = bf16_rne(v.x - bf16_to_f(h4.x));
        h4.y = bf16_rne(v.y); l4.y = bf16_rne(v.y - bf16_to_f(h4.y));
        h4.z = bf16_rne(v.z); l4.z = bf16_rne(v.z - bf16_to_f(h4.z));
        h4.w = bf16_rne(v.w); l4.w = bf16_rne(v.w - bf16_to_f(h4.w));
        *(ushort4*)&h_hi[r * HS + k] = h4;
        *(ushort4*)&h_lo[r * HS + k] = l4;
    }
    __syncthreads();   // all hacc reads done before weights overwrite it

    // ---------------- MLP phases (pre-split weights: pure LDS copy)
    stage_w_pre(wsp, w_hi, w_lo, t);
    if (t < H) bl[t] = b1[t];
    __syncthreads();

    f32x4 acc[8];

    compute_gemm(h_hi, h_lo, w_hi, w_lo, bl, wv, lr, quad, acc);
    __syncthreads();
    epilogue_silu(h_hi, h_lo, acc, wv, lr, quad);
    stage_w_pre(wsp + 32768, w_hi, w_lo, t);
    if (t < H) bl[t] = b2[t];
    __syncthreads();

    compute_gemm(h_hi, h_lo, w_hi, w_lo, bl, wv, lr, quad, acc);
    __syncthreads();
    epilogue_silu(h_hi, h_lo, acc, wv, lr, quad);
    stage_w_pre(wsp + 65536, w_hi, w_lo, t);
    if (t < H) bl[t] = b3[t];
    __syncthreads();

    compute_gemm(h_hi, h_lo, w_hi, w_lo, bl, wv, lr, quad, acc);
    __syncthreads();
    epilogue_silu(h_hi, h_lo, acc, wv, lr, quad);
    stage_w_pre(wsp + 98304, w_hi, w_lo, t);
    if (t < H) bl[t] = 0.f;
    __syncthreads();

    compute_gemm(h_hi, h_lo, w_hi, w_lo, bl, wv, lr, quad, acc);

    #pragma unroll
    for (int ct = 0; ct < 8; ++ct)
        #pragma unroll
        for (int r = 0; r < 4; ++r) {
            const int row = row0 + wv * 16 + quad * 4 + r;
            if (row < N) out[(size_t)row * H + ct * 16 + lr] = acc[ct][r];
        }
}

// ---------------------------------------------------------------- launch
static inline size_t align256(size_t v) { return (v + 255) & ~(size_t)255; }

extern "C" void kernel_launch(void* const* d_in, const int* in_sizes, int n_in,
                              void* d_out, int out_size, void* d_ws, size_t ws_size,
                              hipStream_t stream) {
    const float* x     = (const float*)d_in[0];
    const float* rbf   = (const float*)d_in[1];
    const int*   idx   = (const int*)d_in[2];
    const float* W_rbf = (const float*)d_in[4];
    const float* W1    = (const float*)d_in[5];
    const float* b1    = (const float*)d_in[6];
    const float* W2    = (const float*)d_in[7];
    const float* b2    = (const float*)d_in[8];
    const float* W3    = (const float*)d_in[9];
    const float* b3    = (const float*)d_in[10];
    const float* Wo    = (const float*)d_in[11];
    float* out = (float*)d_out;

    const int E = in_sizes[0] / H;
    const int N = out_size / H;

    char* ws = (char*)d_ws;
    size_t off = 0;
    unsigned short* wsp = (unsigned short*)(ws + off);
    off = align256(off + (size_t)4 * 2 * H * H * sizeof(unsigned short));
    int* counts  = (int*)(ws + off);   off = align256(off + (size_t)N * 4);
    int* cursor  = (int*)(ws + off);   off = align256(off + (size_t)N * 4);
    int* offsets = (int*)(ws + off);   off = align256(off + (size_t)(N + 1) * 4);
    int* elist   = (int*)(ws + off);   off = align256(off + (size_t)E * 4);

    hipMemsetAsync(counts, 0, (char*)offsets - (char*)counts, stream);

    wsplit_k<<<dim3(16, 4), 256, 0, stream>>>(W1, W2, W3, Wo, wsp);
    hist_k<<<(E / 4 + 255) / 256, 256, 0, stream>>>(idx, counts, E);
    scan_k<<<1, 1024, 0, stream>>>(counts, offsets, N);
    fill_k<<<(E / 4 + 255) / 256, 256, 0, stream>>>(idx, offsets, cursor, elist, E);
    fused_mlp<<<(N + MT - 1) / MT, 512, 0, stream>>>(
        x, rbf, W_rbf, offsets, elist, wsp, b1, b2, b3, out, N);
}